// Round 9
// baseline (60.024 us; speedup 1.0000x reference)
//
#include <hip/hip_runtime.h>

#define B_      64
#define L_      8192
#define NB_     20
#define K_      769
#define GLEN    1537        // 2K-1 combined filter length
#define GSM     1552        // g row length (f32), = 97*16
#define NSTEP   97
#define NSTEPP  104         // padded steps (zeros beyond 97) for blind prefetch
#define TB      512         // t-tile per block
#define CPS_H   2072        // copy stride (halves): 16B-aligned, quad-skew
#define NW      2072        // staged halves per copy
#define XCP_N   (8 * CPS_H + 160)   // + pad: blind ring prefetch past last stripe
#define PADLEN  2307        // min(3K, L-1)
#define OFFSET  1539        // PADLEN - (K-1)
#define PBUF    (NB_ * GSM) // partial-g buffer stride (floats)

typedef _Float16 half8  __attribute__((ext_vector_type(8)));
typedef float    f32x16 __attribute__((ext_vector_type(16)));

#define MFMA(a, b, c) __builtin_amdgcn_mfma_f32_32x32x16_f16((a), (b), (c), 0, 0, 0)

// LLVM SchedGroupMask: MFMA=0x8, VMEM_READ=0x20, DS_READ=0x100
#define STEP_SCHED()                                          \
    do {                                                      \
        __builtin_amdgcn_sched_group_barrier(0x008, 4, 0);    \
        __builtin_amdgcn_sched_group_barrier(0x100, 1, 0);    \
        __builtin_amdgcn_sched_group_barrier(0x020, 1, 0);    \
    } while (0)

// ---------------------------------------------------------------------------
// Kernel 1: partial autocorrelation. grid (NB, 8, 4): j-range split 4-way.
// ---------------------------------------------------------------------------
__global__ __launch_bounds__(256) void bp_combine(
    const float* __restrict__ kern, float* __restrict__ gpart)
{
    __shared__ __align__(16) float ks[K_];
    const int o   = blockIdx.x;
    const int jc  = blockIdx.z;
    const int tid = threadIdx.x;
    for (int i = tid; i < K_; i += 256) ks[i] = kern[o * K_ + i];
    __syncthreads();

    const int m = blockIdx.y * 194 + tid;
    if (tid < 194 && m < GSM) {
        float acc = 0.f;
        int jlo = (m > K_ - 1) ? (m - (K_ - 1)) : 0;
        int jhi = (m < K_ - 1) ? m : (K_ - 1);
        if (jlo < jc * 193) jlo = jc * 193;
        if (jhi > jc * 193 + 192) jhi = jc * 193 + 192;
        for (int j = jlo; j <= jhi; ++j)
            acc = fmaf(ks[K_ - 1 - j], ks[m - j], acc);
        gpart[jc * PBUF + o * GSM + m] = acc;
    }
}

// ---------------------------------------------------------------------------
// Kernel 2: sum partials, scale x1024, pack into MFMA A-fragment layout (f16).
// Fragment t = step*64 + l: elem e = g1024[o = l&31, 16*step + 8*(l>>5) + e]
// ---------------------------------------------------------------------------
__global__ __launch_bounds__(256) void bp_pack(
    const float* __restrict__ gpart, _Float16* __restrict__ gbuf)
{
    const int t = blockIdx.x * 256 + threadIdx.x;
    if (t >= NSTEPP * 64) return;
    const int step = t >> 6;
    const int l    = t & 63;
    const int o    = l & 31;
    const int h5   = l >> 5;
    half8 f;
    #pragma unroll
    for (int e = 0; e < 8; ++e) {
        const int tap = 16 * step + 8 * h5 + e;
        float v = 0.f;
        if (o < NB_ && tap < GLEN) {
            const int idx = o * GSM + tap;
            v = (gpart[idx] + gpart[PBUF + idx] +
                 gpart[2 * PBUF + idx] + gpart[3 * PBUF + idx]) * 1024.0f;
        }
        f[e] = (_Float16)v;
    }
    *((half8*)gbuf + t) = f;
}

// ---------------------------------------------------------------------------
// Kernel 3: C[o, t] = sum_k g[o,k] * Toeplitz(xp)[k, t] via mfma 32x32x16 f16.
// Barrier-free K-loop with deep prefetch rings (gq[8], E[6]/O[6]) and
// per-step sched_group_barrier {4 MFMA, 1 DS_READ, 1 VMEM_READ} to pin the
// refill loads at their issue slots (compiler otherwise sinks them to uses,
// collapsing the prefetch distance -- r8 VGPR=80 evidence).
// ---------------------------------------------------------------------------
__global__ __launch_bounds__(256, 2) void bp_mfma(
    const float* __restrict__ x, const _Float16* __restrict__ gbuf,
    float* __restrict__ out)
{
    __shared__ __align__(16) _Float16 xcp[XCP_N];   // 33.5 KB

    const int blk  = blockIdx.x;
    const int tile = blk & 15;              // L/TB = 16
    const int b    = blk >> 4;
    const int tid  = threadIdx.x;
    const int l    = tid & 63;
    const int w    = tid >> 6;

    const int T0 = tile * TB;
    const float* __restrict__ xrow = x + b * L_;

    // ---- two-phase staging: 9 independent loads first, then LDS writes ----
    float xv[9];
    #pragma unroll
    for (int r = 0; r < 9; ++r) {
        const int i = tid + 256 * r;
        if (i < NW) {
            const int p = T0 + OFFSET + i;
            float v;
            if (p < PADLEN)            v = -xrow[PADLEN - p];
            else if (p < PADLEN + L_)  v =  xrow[p - PADLEN];
            else                       v = -xrow[(L_ - 2) + (PADLEN + L_) - p];
            xv[r] = v;
        }
    }
    #pragma unroll
    for (int r = 0; r < 9; ++r) {
        const int i = tid + 256 * r;
        if (i < NW) {
            const _Float16 h = (_Float16)xv[r];
            #pragma unroll
            for (int cc = 0; cc < 8; ++cc) {
                const int j = i - cc;
                if (j >= 0) xcp[cc * CPS_H + j] = h;
            }
        }
    }
    __syncthreads();          // the only barrier

    const int c  = l & 7;
    const int u  = l & 31;
    const int h5 = l >> 5;

    f32x16 acc[4];
    #pragma unroll
    for (int q = 0; q < 4; ++q)
        #pragma unroll
        for (int r = 0; r < 16; ++r) acc[q][r] = 0.f;

    // fragment base: 16B-aligned via parity copy c = l&7
    const char* lb0 = (const char*)xcp + c * (CPS_H * 2)
                    + 2 * (128 * w + u + 8 * h5 - c);

    // x rings: fragment(q, S) lives at byte lb0 + 32*S + 64*q.
    // E (even S): phase e = (S/2)%6, MFMA q reads E[(e+q)%6], refill E[e]
    // with byte 32*S + 384 (= fragment(3, S+6): 6-step distance). O likewise.
    half8 E[6], O[6];
    #pragma unroll
    for (int j = 0; j < 6; ++j) {
        E[j] = *(const half8*)(lb0 + 64 * j);
        O[j] = *(const half8*)(lb0 + 32 + 64 * j);
    }

    // g ring: gq[s&7] holds step s; refill with step s+8 after use.
    const half8* __restrict__ gp = (const half8*)gbuf + l;
    half8 gq[8];
    #pragma unroll
    for (int j = 0; j < 8; ++j) gq[j] = gp[64 * j];

    for (int n = 0; n < 4; ++n) {           // 4 x 24 steps = 96
        const char*  lbn = lb0 + 768 * n;   // 32 * 24n
        const half8* gpn = gp + 64 * 24 * n;
        #pragma unroll
        for (int k = 0; k < 24; ++k) {      // all ring indices static in k
            const int gs = k & 7;           // 24 % 8 == 0
            __builtin_amdgcn_s_setprio(1);
            if ((k & 1) == 0) {
                const int e = (k >> 1) % 6; // 24/2 % 6 == 0
                acc[0] = MFMA(gq[gs], E[(e + 0) % 6], acc[0]);
                acc[1] = MFMA(gq[gs], E[(e + 1) % 6], acc[1]);
                acc[2] = MFMA(gq[gs], E[(e + 2) % 6], acc[2]);
                acc[3] = MFMA(gq[gs], E[(e + 3) % 6], acc[3]);
                __builtin_amdgcn_s_setprio(0);
                E[e] = *(const half8*)(lbn + 32 * k + 384);
            } else {
                const int o2 = ((k - 1) >> 1) % 6;
                acc[0] = MFMA(gq[gs], O[(o2 + 0) % 6], acc[0]);
                acc[1] = MFMA(gq[gs], O[(o2 + 1) % 6], acc[1]);
                acc[2] = MFMA(gq[gs], O[(o2 + 2) % 6], acc[2]);
                acc[3] = MFMA(gq[gs], O[(o2 + 3) % 6], acc[3]);
                __builtin_amdgcn_s_setprio(0);
                O[o2] = *(const half8*)(lbn + 32 * k + 384);
            }
            gq[gs] = gpn[64 * (k + 8)];     // zeros beyond step 96: safe
            STEP_SCHED();                   // pin {4 MFMA, 1 ds_read, 1 vmem}
        }
    }

    // tail: step 96 (even, e = 48%6 = 0): E[0..3] hold fragments(q, 96);
    // gq[96&7 = 0] was refilled at step 88 with step 96's g.
    __builtin_amdgcn_s_setprio(1);
    acc[0] = MFMA(gq[0], E[0], acc[0]);
    acc[1] = MFMA(gq[0], E[1], acc[1]);
    acc[2] = MFMA(gq[0], E[2], acc[2]);
    acc[3] = MFMA(gq[0], E[3], acc[3]);
    __builtin_amdgcn_s_setprio(0);

    // D layout: col = l&31 (t-local), row = (r&3)+8*(r>>2)+4*(l>>5) (o)
    // Non-temporal stores: keep the 42 MB output stream out of L2.
    const float sc = 1.0f / 1024.0f;
    #pragma unroll
    for (int q = 0; q < 4; ++q) {
        const int tb = T0 + 32 * (4 * w + q) + u;
        #pragma unroll
        for (int r = 0; r < 16; ++r) {
            const int o = (r & 3) + 8 * (r >> 2) + 4 * h5;
            if (o < NB_)
                __builtin_nontemporal_store(acc[q][r] * sc,
                                            &out[((b * NB_ + o) << 13) + tb]);
        }
    }
}

extern "C" void kernel_launch(void* const* d_in, const int* in_sizes, int n_in,
                              void* d_out, int out_size, void* d_ws, size_t ws_size,
                              hipStream_t stream)
{
    const float* x    = (const float*)d_in[0];   // (B,1,L) f32
    const float* kern = (const float*)d_in[1];   // (NB,K) f32
    float*       out  = (float*)d_out;           // (B,1,NB,L) f32

    float*    gpart = (float*)d_ws;                           // 496640 B
    _Float16* gbuf  = (_Float16*)((char*)d_ws + 496640);      // 104 KB

    bp_combine<<<dim3(NB_, 8, 4), 256, 0, stream>>>(kern, gpart);
    bp_pack<<<26, 256, 0, stream>>>(gpart, gbuf);
    bp_mfma<<<B_ * (L_ / TB), 256, 0, stream>>>(x, gbuf, out);
}

// Round 10
// 55.632 us; speedup vs baseline: 1.0789x; 1.0789x over previous
//
#include <hip/hip_runtime.h>

#define B_      64
#define L_      8192
#define NB_     20
#define K_      769
#define GLEN    1537        // 2K-1 combined filter length
#define GSM     1552        // g row length (f32), = 97*16
#define NSTEP   97
#define NSTEPP  104         // padded steps (zeros beyond 97) for blind prefetch
#define TB      1024        // t-tile per block (4 waves x 256 t)
#define CPS_H   2600        // copy stride (halves): 16B-aligned; 5200B mod 128 = 80 -> copies skewed across bank groups
#define NW      2600        // staged halves per copy (need 2571 + blind-read slack)
#define XCP_N   (8 * CPS_H + 32)
#define PADLEN  2307        // min(3K, L-1)
#define OFFSET  1539        // PADLEN - (K-1)
#define PBUF    (NB_ * GSM) // partial-g buffer stride (floats)

typedef _Float16 half8  __attribute__((ext_vector_type(8)));
typedef float    f32x16 __attribute__((ext_vector_type(16)));

#define MFMA(a, b, c) __builtin_amdgcn_mfma_f32_32x32x16_f16((a), (b), (c), 0, 0, 0)

// ---------------------------------------------------------------------------
// Kernel 1: partial autocorrelation. grid (NB, 8, 4): j-range split 4-way.
// ---------------------------------------------------------------------------
__global__ __launch_bounds__(256) void bp_combine(
    const float* __restrict__ kern, float* __restrict__ gpart)
{
    __shared__ __align__(16) float ks[K_];
    const int o   = blockIdx.x;
    const int jc  = blockIdx.z;
    const int tid = threadIdx.x;
    for (int i = tid; i < K_; i += 256) ks[i] = kern[o * K_ + i];
    __syncthreads();

    const int m = blockIdx.y * 194 + tid;
    if (tid < 194 && m < GSM) {
        float acc = 0.f;
        int jlo = (m > K_ - 1) ? (m - (K_ - 1)) : 0;
        int jhi = (m < K_ - 1) ? m : (K_ - 1);
        if (jlo < jc * 193) jlo = jc * 193;
        if (jhi > jc * 193 + 192) jhi = jc * 193 + 192;
        for (int j = jlo; j <= jhi; ++j)
            acc = fmaf(ks[K_ - 1 - j], ks[m - j], acc);
        gpart[jc * PBUF + o * GSM + m] = acc;
    }
}

// ---------------------------------------------------------------------------
// Kernel 2: sum partials, scale x1024, pack into MFMA A-fragment layout (f16).
// Fragment t = step*64 + l: elem e = g1024[o = l&31, 16*step + 8*(l>>5) + e]
// ---------------------------------------------------------------------------
__global__ __launch_bounds__(256) void bp_pack(
    const float* __restrict__ gpart, _Float16* __restrict__ gbuf)
{
    const int t = blockIdx.x * 256 + threadIdx.x;
    if (t >= NSTEPP * 64) return;
    const int step = t >> 6;
    const int l    = t & 63;
    const int o    = l & 31;
    const int h5   = l >> 5;
    half8 f;
    #pragma unroll
    for (int e = 0; e < 8; ++e) {
        const int tap = 16 * step + 8 * h5 + e;
        float v = 0.f;
        if (o < NB_ && tap < GLEN) {
            const int idx = o * GSM + tap;
            v = (gpart[idx] + gpart[PBUF + idx] +
                 gpart[2 * PBUF + idx] + gpart[3 * PBUF + idx]) * 1024.0f;
        }
        f[e] = (_Float16)v;
    }
    *((half8*)gbuf + t) = f;
}

// ---------------------------------------------------------------------------
// Kernel 3: C[o, t] = sum_k g[o,k] * Toeplitz(xp)[k, t] via mfma 32x32x16 f16.
// 8 subtiles per wave (256 t): per K-step = 8 MFMA (256 issue cyc) vs
// 1 ds_read_b128 + 1 global g-load -- stall amortized 2x vs the 4-subtile
// version, so 2 waves/SIMD of TLP suffice to keep the matrix pipe fed.
// Rings: E[8]/O[8] x-fragments (even/odd steps), gq[8] g steps; inner
// unroll of 16 steps makes every ring index static. Grid = 512 blocks =
// exactly 2 blocks/CU (zero tail).
// ---------------------------------------------------------------------------
__global__ __launch_bounds__(256, 2) void bp_mfma(
    const float* __restrict__ x, const _Float16* __restrict__ gbuf,
    float* __restrict__ out)
{
    __shared__ __align__(16) _Float16 xcp[XCP_N];   // 40.7 KB

    const int blk  = blockIdx.x;
    const int tile = blk & 7;               // L/TB = 8
    const int b    = blk >> 3;
    const int tid  = threadIdx.x;
    const int l    = tid & 63;
    const int w    = tid >> 6;

    const int T0 = tile * TB;
    const float* __restrict__ xrow = x + b * L_;

    // ---- two-phase staging: independent loads first, then LDS writes ----
    float xv[11];
    #pragma unroll
    for (int r = 0; r < 11; ++r) {
        const int i = tid + 256 * r;
        if (i < NW) {
            const int p = T0 + OFFSET + i;
            float v;
            if (p < PADLEN)            v = -xrow[PADLEN - p];
            else if (p < PADLEN + L_)  v =  xrow[p - PADLEN];
            else                       v = -xrow[(L_ - 2) + (PADLEN + L_) - p];
            xv[r] = v;
        }
    }
    #pragma unroll
    for (int r = 0; r < 11; ++r) {
        const int i = tid + 256 * r;
        if (i < NW) {
            const _Float16 h = (_Float16)xv[r];
            #pragma unroll
            for (int cc = 0; cc < 8; ++cc) {
                const int j = i - cc;
                if (j >= 0) xcp[cc * CPS_H + j] = h;
            }
        }
    }
    __syncthreads();          // the only barrier

    const int c  = l & 7;
    const int u  = l & 31;
    const int h5 = l >> 5;

    f32x16 acc[8];
    #pragma unroll
    for (int q = 0; q < 8; ++q)
        #pragma unroll
        for (int r = 0; r < 16; ++r) acc[q][r] = 0.f;

    // fragment base: 16B-aligned via parity copy c = l&7.
    // frag(q, S) lives at byte lb0 + 32*S + 64*q  (wave covers 256 t: 512B).
    const char* lb0 = (const char*)xcp + c * (CPS_H * 2)
                    + 2 * (256 * w + u + 8 * h5 - c);

    // x rings: even steps use E[((S/2)+q)&7], odd steps O likewise.
    // After step S, vacated slot is refilled with frag(7, S+2) = +512 bytes.
    half8 E[8], O[8];
    #pragma unroll
    for (int j = 0; j < 8; ++j) {
        E[j] = *(const half8*)(lb0 + 64 * j);
        O[j] = *(const half8*)(lb0 + 32 + 64 * j);
    }

    // g ring: gq[s&7] holds step s; refill with step s+8 after use.
    const half8* __restrict__ gp = (const half8*)gbuf + l;
    half8 gq[8];
    #pragma unroll
    for (int j = 0; j < 8; ++j) gq[j] = gp[64 * j];

    for (int n = 0; n < 6; ++n) {           // 6 x 16 steps = 96
        const char*  lbn = lb0 + 512 * n;   // 32 * 16n
        const half8* gpn = gp + 64 * 16 * n;
        #pragma unroll
        for (int k = 0; k < 16; ++k) {      // all ring indices static in k
            const int gs = k & 7;
            const int ph = (k >> 1) & 7;    // (S/2)&7 for even, ((S-1)/2)&7 for odd
            __builtin_amdgcn_s_setprio(1);
            if ((k & 1) == 0) {
                acc[0] = MFMA(gq[gs], E[(ph + 0) & 7], acc[0]);
                acc[1] = MFMA(gq[gs], E[(ph + 1) & 7], acc[1]);
                acc[2] = MFMA(gq[gs], E[(ph + 2) & 7], acc[2]);
                acc[3] = MFMA(gq[gs], E[(ph + 3) & 7], acc[3]);
                acc[4] = MFMA(gq[gs], E[(ph + 4) & 7], acc[4]);
                acc[5] = MFMA(gq[gs], E[(ph + 5) & 7], acc[5]);
                acc[6] = MFMA(gq[gs], E[(ph + 6) & 7], acc[6]);
                acc[7] = MFMA(gq[gs], E[(ph + 7) & 7], acc[7]);
                __builtin_amdgcn_s_setprio(0);
                E[ph] = *(const half8*)(lbn + 32 * k + 512);   // frag(7, S+2)
            } else {
                acc[0] = MFMA(gq[gs], O[(ph + 0) & 7], acc[0]);
                acc[1] = MFMA(gq[gs], O[(ph + 1) & 7], acc[1]);
                acc[2] = MFMA(gq[gs], O[(ph + 2) & 7], acc[2]);
                acc[3] = MFMA(gq[gs], O[(ph + 3) & 7], acc[3]);
                acc[4] = MFMA(gq[gs], O[(ph + 4) & 7], acc[4]);
                acc[5] = MFMA(gq[gs], O[(ph + 5) & 7], acc[5]);
                acc[6] = MFMA(gq[gs], O[(ph + 6) & 7], acc[6]);
                acc[7] = MFMA(gq[gs], O[(ph + 7) & 7], acc[7]);
                __builtin_amdgcn_s_setprio(0);
                O[ph] = *(const half8*)(lbn + 32 * k + 512);   // frag(7, S+2)
            }
            gq[gs] = gpn[64 * (k + 8)];     // zeros beyond step 96: safe
        }
    }

    // tail: step 96 (even, phase (96/2)&7 = 0): E[q] holds frag(q, 96);
    // gq[0] was refilled at step 88 with step 96's g.
    __builtin_amdgcn_s_setprio(1);
    acc[0] = MFMA(gq[0], E[0], acc[0]);
    acc[1] = MFMA(gq[0], E[1], acc[1]);
    acc[2] = MFMA(gq[0], E[2], acc[2]);
    acc[3] = MFMA(gq[0], E[3], acc[3]);
    acc[4] = MFMA(gq[0], E[4], acc[4]);
    acc[5] = MFMA(gq[0], E[5], acc[5]);
    acc[6] = MFMA(gq[0], E[6], acc[6]);
    acc[7] = MFMA(gq[0], E[7], acc[7]);
    __builtin_amdgcn_s_setprio(0);

    // D layout: col = l&31 (t-local), row = (r&3)+8*(r>>2)+4*(l>>5) (o)
    // Non-temporal stores: keep the 42 MB output stream out of L2.
    const float sc = 1.0f / 1024.0f;
    #pragma unroll
    for (int q = 0; q < 8; ++q) {
        const int tb = T0 + 32 * (8 * w + q) + u;
        #pragma unroll
        for (int r = 0; r < 16; ++r) {
            const int o = (r & 3) + 8 * (r >> 2) + 4 * h5;
            if (o < NB_)
                __builtin_nontemporal_store(acc[q][r] * sc,
                                            &out[((b * NB_ + o) << 13) + tb]);
        }
    }
}

extern "C" void kernel_launch(void* const* d_in, const int* in_sizes, int n_in,
                              void* d_out, int out_size, void* d_ws, size_t ws_size,
                              hipStream_t stream)
{
    const float* x    = (const float*)d_in[0];   // (B,1,L) f32
    const float* kern = (const float*)d_in[1];   // (NB,K) f32
    float*       out  = (float*)d_out;           // (B,1,NB,L) f32

    float*    gpart = (float*)d_ws;                           // 496640 B
    _Float16* gbuf  = (_Float16*)((char*)d_ws + 496640);      // 104 KB

    bp_combine<<<dim3(NB_, 8, 4), 256, 0, stream>>>(kern, gpart);
    bp_pack<<<26, 256, 0, stream>>>(gpart, gbuf);
    bp_mfma<<<B_ * (L_ / TB), 256, 0, stream>>>(x, gbuf, out);
}

// Round 11
// 46.941 us; speedup vs baseline: 1.2787x; 1.1852x over previous
//
#include <hip/hip_runtime.h>

#define B_      64
#define L_      8192
#define NB_     20
#define K_      769
#define GLEN    1537        // 2K-1 combined filter length
#define GSM     1552        // g row length (f32)
#define NSTEP2  49          // folded K-steps: 49*16 = 784 taps (768 pairs + center)
#define NSTEPP2 56          // padded steps (zeros beyond 49) for blind gq prefetch
#define TB      512         // t-tile per block (4 waves x 128 t, 4 subtiles/wave)
#define CPF     1416        // copy stride (halves): 16B-aligned, 2832B mod 128 = 16 -> 8 copies span all banks
#define NWF     1376        // forward staged halves per copy (max read 1303)
#define NWB     1344        // backward staged halves per copy (max read 1304)
#define PADLEN  2307        // min(3K, L-1)
#define OFFSET  1539        // PADLEN - (K-1)
#define PBUF    (NB_ * GSM) // partial-g buffer stride (floats)

typedef _Float16 half8  __attribute__((ext_vector_type(8)));
typedef float    f32x16 __attribute__((ext_vector_type(16)));

#define MFMA(a, b, c) __builtin_amdgcn_mfma_f32_32x32x16_f16((a), (b), (c), 0, 0, 0)

// ---------------------------------------------------------------------------
// Kernel 1: partial autocorrelation. grid (NB, 8, 4): j-range split 4-way.
// ---------------------------------------------------------------------------
__global__ __launch_bounds__(256) void bp_combine(
    const float* __restrict__ kern, float* __restrict__ gpart)
{
    __shared__ __align__(16) float ks[K_];
    const int o   = blockIdx.x;
    const int jc  = blockIdx.z;
    const int tid = threadIdx.x;
    for (int i = tid; i < K_; i += 256) ks[i] = kern[o * K_ + i];
    __syncthreads();

    const int m = blockIdx.y * 194 + tid;
    if (tid < 194 && m < GSM) {
        float acc = 0.f;
        int jlo = (m > K_ - 1) ? (m - (K_ - 1)) : 0;
        int jhi = (m < K_ - 1) ? m : (K_ - 1);
        if (jlo < jc * 193) jlo = jc * 193;
        if (jhi > jc * 193 + 192) jhi = jc * 193 + 192;
        for (int j = jlo; j <= jhi; ++j)
            acc = fmaf(ks[K_ - 1 - j], ks[m - j], acc);
        gpart[jc * PBUF + o * GSM + m] = acc;
    }
}

// ---------------------------------------------------------------------------
// Kernel 2: folded filter g' in MFMA A-fragment layout (f16, scaled x1024).
// g'[tap] = g[tap]       for tap < 768   (pairs with g[1536-tap] via folded B)
//         = g[768]/2     for tap == 768  (folded B doubles the center sample)
//         = 0            for tap > 768
// Fragment t = step*64 + l: elem e = g'[o = l&31, 16*step + 8*(l>>5) + e]
// ---------------------------------------------------------------------------
__global__ __launch_bounds__(256) void bp_pack(
    const float* __restrict__ gpart, _Float16* __restrict__ gbuf)
{
    const int t = blockIdx.x * 256 + threadIdx.x;
    if (t >= NSTEPP2 * 64) return;
    const int step = t >> 6;
    const int l    = t & 63;
    const int o    = l & 31;
    const int h5   = l >> 5;
    half8 f;
    #pragma unroll
    for (int e = 0; e < 8; ++e) {
        const int tap = 16 * step + 8 * h5 + e;
        float v = 0.f;
        if (o < NB_ && tap <= 768) {
            const int idx = o * GSM + tap;
            const float gg = gpart[idx] + gpart[PBUF + idx] +
                             gpart[2 * PBUF + idx] + gpart[3 * PBUF + idx];
            v = gg * (tap == 768 ? 512.0f : 1024.0f);
        }
        f[e] = (_Float16)v;
    }
    *((half8*)gbuf + t) = f;
}

// ---------------------------------------------------------------------------
// Kernel 3 (folded): z[t] = sum_{k=0}^{783} g'[k] * (xp[t'+k] + xp[t'+1536-k])
// B-fragment = fwd half8 (Toeplitz, from xcp) + bwd half8 (Hankel, from the
// REVERSED staged array xr: xr[j] = xp[P0+2048-j], so bwd is also a
// consecutive ascending read). Both slide: frag(q,S+2)=frag(q+1,S) fwd,
// frag_bw(q,S+2)=frag_bw(q-1,S) bwd -> 4-slot rings, 1 ds_read_b128 each per
// step. 49 K-steps. gq[8] global register ring. Barrier-free, NT stores.
// ---------------------------------------------------------------------------
__global__ __launch_bounds__(256, 2) void bp_mfma(
    const float* __restrict__ x, const _Float16* __restrict__ gbuf,
    float* __restrict__ out)
{
    __shared__ __align__(16) _Float16 xls[16 * CPF + 16];  // fwd copies 0-7, bwd 8-15 (44.3 KB)

    const int blk  = blockIdx.x;
    const int tile = blk & 15;              // L/TB = 16
    const int b    = blk >> 4;
    const int tid  = threadIdx.x;
    const int l    = tid & 63;
    const int w    = tid >> 6;

    const int T0 = tile * TB;
    const int P0 = T0 + OFFSET;
    const float* __restrict__ xrow = x + b * L_;

    // ---- two-phase staging: all global loads first, then LDS writes ----
    // reflect: p<PADLEN -> -x[PADLEN-p]; p<PADLEN+L -> x[p-PADLEN]; else -x[(L-2)+(PADLEN+L)-p]
    float fv[6], bv[6];
    #pragma unroll
    for (int r = 0; r < 6; ++r) {
        const int i = tid + 256 * r;
        if (i < NWF) {
            const int p = P0 + i;
            fv[r] = (p < PADLEN) ? -xrow[PADLEN - p]
                  : (p < PADLEN + L_) ? xrow[p - PADLEN]
                  : -xrow[(L_ - 2) + (PADLEN + L_) - p];
        }
        const int j = tid + 256 * r;
        if (j < NWB) {
            const int p = P0 + 2048 - j;
            bv[r] = (p < PADLEN) ? -xrow[PADLEN - p]
                  : (p < PADLEN + L_) ? xrow[p - PADLEN]
                  : -xrow[(L_ - 2) + (PADLEN + L_) - p];
        }
    }
    #pragma unroll
    for (int r = 0; r < 6; ++r) {
        const int i = tid + 256 * r;
        if (i < NWF) {
            const _Float16 h = (_Float16)fv[r];
            #pragma unroll
            for (int cc = 0; cc < 8; ++cc)
                if (i - cc >= 0) xls[cc * CPF + (i - cc)] = h;
        }
        const int j = tid + 256 * r;
        if (j < NWB) {
            const _Float16 h = (_Float16)bv[r];
            #pragma unroll
            for (int cc = 0; cc < 8; ++cc)
                if (j - cc >= 0) xls[(8 + cc) * CPF + (j - cc)] = h;
        }
    }
    __syncthreads();          // the only barrier

    const int u  = l & 31;
    const int h5 = l >> 5;
    const int c  = l & 7;                   // fwd parity copy
    const int c2 = (-l) & 7;                // bwd parity copy

    f32x16 acc[4];
    #pragma unroll
    for (int q = 0; q < 4; ++q)
        #pragma unroll
        for (int r = 0; r < 16; ++r) acc[q][r] = 0.f;

    // fwd frag(q,S) at byte lb0 + 32S + 64q ; bwd frag_bw(q,S) at lbb0 + 32S - 64q
    const char* lb0  = (const char*)xls + c * (CPF * 2)
                     + 2 * (128 * w + u + 8 * h5 - c);
    const char* lbb0 = (const char*)xls + (8 + c2) * (CPF * 2)
                     + 2 * (512 - 128 * w - u + 8 * h5 - c2);

    // rings: even steps E/Eb, odd steps O/Ob. ph=(S/2)&3.
    // fwd consume E[(ph+q)&3], refill E[ph] <- frag(3,S+2) = byte 32S+256.
    // bwd consume Eb[(ph-q)&3], refill Eb[(ph+1)&3] <- frag_bw(0,S+2) = 32S+64.
    half8 E[4], O[4], Eb[4], Ob[4];
    #pragma unroll
    for (int j = 0; j < 4; ++j) {
        E[j] = *(const half8*)(lb0 + 64 * j);
        O[j] = *(const half8*)(lb0 + 32 + 64 * j);
    }
    Eb[0] = *(const half8*)(lbb0);          // frag_bw(0,0)
    Eb[3] = *(const half8*)(lbb0 - 64);     // frag_bw(1,0)
    Eb[2] = *(const half8*)(lbb0 - 128);    // frag_bw(2,0)
    Eb[1] = *(const half8*)(lbb0 - 192);    // frag_bw(3,0)
    Ob[0] = *(const half8*)(lbb0 + 32);
    Ob[3] = *(const half8*)(lbb0 + 32 - 64);
    Ob[2] = *(const half8*)(lbb0 + 32 - 128);
    Ob[1] = *(const half8*)(lbb0 + 32 - 192);

    // g ring: gq[s&7] holds step s; refill with step s+8 after use.
    const half8* __restrict__ gp = (const half8*)gbuf + l;
    half8 gq[8];
    #pragma unroll
    for (int j = 0; j < 8; ++j) gq[j] = gp[64 * j];

    for (int n = 0; n < 3; ++n) {           // 3 x 16 steps = 48
        const char*  lbf = lb0 + 512 * n;
        const char*  lbb = lbb0 + 512 * n;
        const half8* gpn = gp + 64 * 16 * n;
        #pragma unroll
        for (int k = 0; k < 16; ++k) {      // all ring indices static in k
            const int gs = k & 7;
            const int ph = (k >> 1) & 3;
            __builtin_amdgcn_s_setprio(1);
            if ((k & 1) == 0) {
                acc[0] = MFMA(gq[gs], E[(ph + 0) & 3] + Eb[(ph + 4 - 0) & 3], acc[0]);
                acc[1] = MFMA(gq[gs], E[(ph + 1) & 3] + Eb[(ph + 4 - 1) & 3], acc[1]);
                acc[2] = MFMA(gq[gs], E[(ph + 2) & 3] + Eb[(ph + 4 - 2) & 3], acc[2]);
                acc[3] = MFMA(gq[gs], E[(ph + 3) & 3] + Eb[(ph + 4 - 3) & 3], acc[3]);
                __builtin_amdgcn_s_setprio(0);
                E[ph]            = *(const half8*)(lbf + 32 * k + 256);
                Eb[(ph + 1) & 3] = *(const half8*)(lbb + 32 * k + 64);
            } else {
                acc[0] = MFMA(gq[gs], O[(ph + 0) & 3] + Ob[(ph + 4 - 0) & 3], acc[0]);
                acc[1] = MFMA(gq[gs], O[(ph + 1) & 3] + Ob[(ph + 4 - 1) & 3], acc[1]);
                acc[2] = MFMA(gq[gs], O[(ph + 2) & 3] + Ob[(ph + 4 - 2) & 3], acc[2]);
                acc[3] = MFMA(gq[gs], O[(ph + 3) & 3] + Ob[(ph + 4 - 3) & 3], acc[3]);
                __builtin_amdgcn_s_setprio(0);
                O[ph]            = *(const half8*)(lbf + 32 * k + 256);
                Ob[(ph + 1) & 3] = *(const half8*)(lbb + 32 * k + 64);
            }
            gq[gs] = gpn[64 * (k + 8)];     // zeros beyond step 48: safe
        }
    }

    // tail: step 48 (even, ph=0): E[q] = frag(q,48), Eb[(4-q)&3] = frag_bw(q,48),
    // gq[48&7=0] refilled at step 40 with step 48's g.
    __builtin_amdgcn_s_setprio(1);
    acc[0] = MFMA(gq[0], E[0] + Eb[0], acc[0]);
    acc[1] = MFMA(gq[0], E[1] + Eb[3], acc[1]);
    acc[2] = MFMA(gq[0], E[2] + Eb[2], acc[2]);
    acc[3] = MFMA(gq[0], E[3] + Eb[1], acc[3]);
    __builtin_amdgcn_s_setprio(0);

    // D layout: col = l&31 (t-local), row = (r&3)+8*(r>>2)+4*(l>>5) (o)
    const float sc = 1.0f / 1024.0f;
    #pragma unroll
    for (int q = 0; q < 4; ++q) {
        const int tb = T0 + 128 * w + 32 * q + u;
        #pragma unroll
        for (int r = 0; r < 16; ++r) {
            const int o = (r & 3) + 8 * (r >> 2) + 4 * h5;
            if (o < NB_)
                __builtin_nontemporal_store(acc[q][r] * sc,
                                            &out[((b * NB_ + o) << 13) + tb]);
        }
    }
}

extern "C" void kernel_launch(void* const* d_in, const int* in_sizes, int n_in,
                              void* d_out, int out_size, void* d_ws, size_t ws_size,
                              hipStream_t stream)
{
    const float* x    = (const float*)d_in[0];   // (B,1,L) f32
    const float* kern = (const float*)d_in[1];   // (NB,K) f32
    float*       out  = (float*)d_out;           // (B,1,NB,L) f32

    float*    gpart = (float*)d_ws;                           // 496640 B
    _Float16* gbuf  = (_Float16*)((char*)d_ws + 496640);      // 56 KB

    bp_combine<<<dim3(NB_, 8, 4), 256, 0, stream>>>(kern, gpart);
    bp_pack<<<14, 256, 0, stream>>>(gpart, gbuf);
    bp_mfma<<<B_ * (L_ / TB), 256, 0, stream>>>(x, gbuf, out);
}

// Round 12
// 45.467 us; speedup vs baseline: 1.3202x; 1.0324x over previous
//
#include <hip/hip_runtime.h>

#define B_      64
#define L_      8192
#define NB_     20
#define K_      769
#define GLEN    1537        // 2K-1 combined filter length
#define GSM     1552        // g row length (f32)
#define NSTEP2  49          // folded K-steps: 49*16 = 784 taps (768 pairs + center)
#define NSTEPP2 56          // packed steps in gbuf (zeros beyond 49)
#define TB      512         // t-tile per block (4 waves x 128 t, 4 subtiles/wave)
#define CPF4    1360        // copy stride (halves) fwd/bwd: 2*1360 mod 128 = 32 -> 4 copies spread banks
#define NWS     1320        // staged halves per direction
#define XBOFF   (4 * CPF4)              // bwd region offset (halves)
#define GOFF    (8 * CPF4)              // g region offset (halves)
#define LDS_H   (8 * CPF4 + NSTEP2 * 512)  // 35968 halves = 71936 B
#define PADLEN  2307        // min(3K, L-1)
#define OFFSET  1539        // PADLEN - (K-1)
#define PBUF    (NB_ * GSM) // partial-g buffer stride (floats)

typedef _Float16 half4  __attribute__((ext_vector_type(4)));
typedef _Float16 half8  __attribute__((ext_vector_type(8)));
typedef float    f32x16 __attribute__((ext_vector_type(16)));

#define MFMA(a, b, c) __builtin_amdgcn_mfma_f32_32x32x16_f16((a), (b), (c), 0, 0, 0)

// 16B fragment via two ds_read_b64 (8B-aligned is enough with 4 parity copies)
__device__ __forceinline__ half8 ld_h8(const char* p) {
    const half4 lo = *(const half4*)p;
    const half4 hi = *(const half4*)(p + 8);
    return __builtin_shufflevector(lo, hi, 0, 1, 2, 3, 4, 5, 6, 7);
}

// ---------------------------------------------------------------------------
// Kernel 1: partial autocorrelation. grid (NB, 8, 4): j-range split 4-way.
// ---------------------------------------------------------------------------
__global__ __launch_bounds__(256) void bp_combine(
    const float* __restrict__ kern, float* __restrict__ gpart)
{
    __shared__ __align__(16) float ks[K_];
    const int o   = blockIdx.x;
    const int jc  = blockIdx.z;
    const int tid = threadIdx.x;
    for (int i = tid; i < K_; i += 256) ks[i] = kern[o * K_ + i];
    __syncthreads();

    const int m = blockIdx.y * 194 + tid;
    if (tid < 194 && m < GSM) {
        float acc = 0.f;
        int jlo = (m > K_ - 1) ? (m - (K_ - 1)) : 0;
        int jhi = (m < K_ - 1) ? m : (K_ - 1);
        if (jlo < jc * 193) jlo = jc * 193;
        if (jhi > jc * 193 + 192) jhi = jc * 193 + 192;
        for (int j = jlo; j <= jhi; ++j)
            acc = fmaf(ks[K_ - 1 - j], ks[m - j], acc);
        gpart[jc * PBUF + o * GSM + m] = acc;
    }
}

// ---------------------------------------------------------------------------
// Kernel 2: folded filter g' in MFMA A-fragment layout (f16, scaled x1024).
// g'[tap<768] = g[tap]; g'[768] = g[768]/2 (folded B doubles center); else 0.
// Fragment t = step*64 + l: elem e = g'[o = l&31, 16*step + 8*(l>>5) + e]
// ---------------------------------------------------------------------------
__global__ __launch_bounds__(256) void bp_pack(
    const float* __restrict__ gpart, _Float16* __restrict__ gbuf)
{
    const int t = blockIdx.x * 256 + threadIdx.x;
    if (t >= NSTEPP2 * 64) return;
    const int step = t >> 6;
    const int l    = t & 63;
    const int o    = l & 31;
    const int h5   = l >> 5;
    half8 f;
    #pragma unroll
    for (int e = 0; e < 8; ++e) {
        const int tap = 16 * step + 8 * h5 + e;
        float v = 0.f;
        if (o < NB_ && tap <= 768) {
            const int idx = o * GSM + tap;
            const float gg = gpart[idx] + gpart[PBUF + idx] +
                             gpart[2 * PBUF + idx] + gpart[3 * PBUF + idx];
            v = gg * (tap == 768 ? 512.0f : 1024.0f);
        }
        f[e] = (_Float16)v;
    }
    *((half8*)gbuf + t) = f;
}

// ---------------------------------------------------------------------------
// Kernel 3 (folded, ALL-LDS K-loop): z[t] = sum_k g'[k]*(xp[t'+k]+xp[t'+1536-k])
// g' staged ONCE into LDS (49 KB) via global_load_lds -> zero global loads in
// the K-loop. x fwd/bwd windows in 4 parity-shifted LDS copies each; fragment
// reads = 2x ds_read_b64. Rings E/O/Eb/Ob[4] (r11 algebra), gq[2] LDS ring.
// LDS 70.3 KB -> 2 blocks/CU. Barrier-free loop, NT stores.
// ---------------------------------------------------------------------------
__global__ __launch_bounds__(256, 2) void bp_mfma(
    const float* __restrict__ x, const _Float16* __restrict__ gbuf,
    float* __restrict__ out)
{
    __shared__ __align__(16) _Float16 lds[LDS_H];

    const int blk  = blockIdx.x;
    const int tile = blk & 15;              // L/TB = 16
    const int b    = blk >> 4;
    const int tid  = threadIdx.x;
    const int l    = tid & 63;
    const int w    = tid >> 6;

    const int T0 = tile * TB;
    const int P0 = T0 + OFFSET;
    const float* __restrict__ xrow = x + b * L_;
    const char*  __restrict__ gsrc = (const char*)gbuf;

    // ---- stage g' into LDS (async, 16B/lane) ----
    #pragma unroll
    for (int it = 0; it < 13; ++it) {
        const int idx = it * 256 + tid;
        if (idx < NSTEP2 * 64) {
            __builtin_amdgcn_global_load_lds(
                (const __attribute__((address_space(1))) void*)(gsrc + (size_t)idx * 16),
                (__attribute__((address_space(3))) void*)&lds[GOFF + (size_t)(it * 256 + (tid & 192)) * 8],
                16, 0, 0);
        }
    }

    // ---- two-phase x staging: global loads first, then LDS writes ----
    // reflect: p<PADLEN -> -x[PADLEN-p]; p<PADLEN+L -> x[p-PADLEN]; else -x[(L-2)+(PADLEN+L)-p]
    float fv[6], bv[6];
    #pragma unroll
    for (int r = 0; r < 6; ++r) {
        const int i = tid + 256 * r;
        if (i < NWS) {
            const int p = P0 + i;
            fv[r] = (p < PADLEN) ? -xrow[PADLEN - p]
                  : (p < PADLEN + L_) ? xrow[p - PADLEN]
                  : -xrow[(L_ - 2) + (PADLEN + L_) - p];
            const int p2 = P0 + 2048 - i;
            bv[r] = (p2 < PADLEN) ? -xrow[PADLEN - p2]
                  : (p2 < PADLEN + L_) ? xrow[p2 - PADLEN]
                  : -xrow[(L_ - 2) + (PADLEN + L_) - p2];
        }
    }
    #pragma unroll
    for (int r = 0; r < 6; ++r) {
        const int i = tid + 256 * r;
        if (i < NWS) {
            const _Float16 hf = (_Float16)fv[r];
            const _Float16 hb = (_Float16)bv[r];
            #pragma unroll
            for (int cc = 0; cc < 4; ++cc) {
                if (i - cc >= 0) {
                    lds[cc * CPF4 + (i - cc)] = hf;            // xf_c[j] = xp[P0+j+c]
                    lds[XBOFF + cc * CPF4 + (i - cc)] = hb;    // xb_c[j] = xp[P0+2048-(j+c)]
                }
            }
        }
    }
    __syncthreads();          // drains global_load_lds + ds_writes

    const int u  = l & 31;
    const int h5 = l >> 5;
    const int c4f = u & 3;
    const int c4b = (512 - u) & 3;          // (o_b0) mod 4

    f32x16 acc[4];
    #pragma unroll
    for (int q = 0; q < 4; ++q)
        #pragma unroll
        for (int r = 0; r < 16; ++r) acc[q][r] = 0.f;

    // fwd frag(q,S): bytes lbf0 + 32S + 64q (+0,+8); bwd frag_bw(q,S): lbb0 + 32S - 64q
    const char* ldsb = (const char*)lds;
    const char* lbf0 = ldsb + 2 * (c4f * CPF4 + (128 * w + u + 8 * h5 - c4f));
    const char* lbb0 = ldsb + 2 * (XBOFF + c4b * CPF4 + (512 - 128 * w - u + 8 * h5 - c4b));
    const char* gpl  = ldsb + 2 * GOFF + l * 16;   // + 1024 per step

    half8 E[4], O[4], Eb[4], Ob[4];
    #pragma unroll
    for (int j = 0; j < 4; ++j) {
        E[j] = ld_h8(lbf0 + 64 * j);        // frag(j,0)
        O[j] = ld_h8(lbf0 + 32 + 64 * j);   // frag(j,1)
    }
    Eb[0] = ld_h8(lbb0);                    // frag_bw(0,0)
    Eb[3] = ld_h8(lbb0 - 64);
    Eb[2] = ld_h8(lbb0 - 128);
    Eb[1] = ld_h8(lbb0 - 192);
    Ob[0] = ld_h8(lbb0 + 32);
    Ob[3] = ld_h8(lbb0 + 32 - 64);
    Ob[2] = ld_h8(lbb0 + 32 - 128);
    Ob[1] = ld_h8(lbb0 + 32 - 192);

    half8 gq[2];
    gq[0] = *(const half8*)(gpl);           // g step 0

    for (int n = 0; n < 3; ++n) {           // 3 x 16 steps = 48
        const char* lbf = lbf0 + 512 * n;
        const char* lbb = lbb0 + 512 * n;
        const char* gst = gpl + 16384 * n;  // 16 steps * 1024 B
        #pragma unroll
        for (int k = 0; k < 16; ++k) {      // all ring indices static in k
            const int ph = (k >> 1) & 3;
            gq[(k + 1) & 1] = *(const half8*)(gst + (k + 1) * 1024);  // g step +1
            __builtin_amdgcn_s_setprio(1);
            if ((k & 1) == 0) {
                acc[0] = MFMA(gq[k & 1], E[(ph + 0) & 3] + Eb[(ph + 4 - 0) & 3], acc[0]);
                acc[1] = MFMA(gq[k & 1], E[(ph + 1) & 3] + Eb[(ph + 4 - 1) & 3], acc[1]);
                acc[2] = MFMA(gq[k & 1], E[(ph + 2) & 3] + Eb[(ph + 4 - 2) & 3], acc[2]);
                acc[3] = MFMA(gq[k & 1], E[(ph + 3) & 3] + Eb[(ph + 4 - 3) & 3], acc[3]);
                __builtin_amdgcn_s_setprio(0);
                E[ph]            = ld_h8(lbf + 32 * k + 256);   // frag(3,S+2)
                Eb[(ph + 1) & 3] = ld_h8(lbb + 32 * k + 64);    // frag_bw(0,S+2)
            } else {
                acc[0] = MFMA(gq[k & 1], O[(ph + 0) & 3] + Ob[(ph + 4 - 0) & 3], acc[0]);
                acc[1] = MFMA(gq[k & 1], O[(ph + 1) & 3] + Ob[(ph + 4 - 1) & 3], acc[1]);
                acc[2] = MFMA(gq[k & 1], O[(ph + 2) & 3] + Ob[(ph + 4 - 2) & 3], acc[2]);
                acc[3] = MFMA(gq[k & 1], O[(ph + 3) & 3] + Ob[(ph + 4 - 3) & 3], acc[3]);
                __builtin_amdgcn_s_setprio(0);
                O[ph]            = ld_h8(lbf + 32 * k + 256);
                Ob[(ph + 1) & 3] = ld_h8(lbb + 32 * k + 64);
            }
        }
    }

    // tail: step 48 (even, ph=0); gq[0] holds step 48 (prefetched at k=15,n=2)
    __builtin_amdgcn_s_setprio(1);
    acc[0] = MFMA(gq[0], E[0] + Eb[0], acc[0]);
    acc[1] = MFMA(gq[0], E[1] + Eb[3], acc[1]);
    acc[2] = MFMA(gq[0], E[2] + Eb[2], acc[2]);
    acc[3] = MFMA(gq[0], E[3] + Eb[1], acc[3]);
    __builtin_amdgcn_s_setprio(0);

    // D layout: col = l&31 (t-local), row = (r&3)+8*(r>>2)+4*(l>>5) (o)
    const float sc = 1.0f / 1024.0f;
    #pragma unroll
    for (int q = 0; q < 4; ++q) {
        const int tb = T0 + 128 * w + 32 * q + u;
        #pragma unroll
        for (int r = 0; r < 16; ++r) {
            const int o = (r & 3) + 8 * (r >> 2) + 4 * h5;
            if (o < NB_)
                __builtin_nontemporal_store(acc[q][r] * sc,
                                            &out[((b * NB_ + o) << 13) + tb]);
        }
    }
}

extern "C" void kernel_launch(void* const* d_in, const int* in_sizes, int n_in,
                              void* d_out, int out_size, void* d_ws, size_t ws_size,
                              hipStream_t stream)
{
    const float* x    = (const float*)d_in[0];   // (B,1,L) f32
    const float* kern = (const float*)d_in[1];   // (NB,K) f32
    float*       out  = (float*)d_out;           // (B,1,NB,L) f32

    float*    gpart = (float*)d_ws;                           // 496640 B
    _Float16* gbuf  = (_Float16*)((char*)d_ws + 496640);      // 56 KB

    bp_combine<<<dim3(NB_, 8, 4), 256, 0, stream>>>(kern, gpart);
    bp_pack<<<14, 256, 0, stream>>>(gpart, gbuf);
    bp_mfma<<<B_ * (L_ / TB), 256, 0, stream>>>(x, gbuf, out);
}

// Round 13
// 45.329 us; speedup vs baseline: 1.3242x; 1.0030x over previous
//
#include <hip/hip_runtime.h>

#define B_      64
#define L_      8192
#define NB_     20
#define K_      769
#define GLEN    1537        // 2K-1 combined filter length
#define GSM     1552        // g row length (f32)
#define NST3    25          // folded K-steps of 32 taps: 25*32 = 800 >= 785
#define NSTP3   28          // packed steps in gbuf (zeros beyond 25) for blind prefetch
#define TB      512         // t-tile per block (4 waves x 128 t, 8 x 16-t subtiles/wave)
#define CPF     1360        // fwd copy stride (halves)
#define CPB     1472        // bwd copy stride (halves)
#define NWF     1360        // fwd staged halves per copy
#define NWB     1472        // bwd staged halves per copy
#define XB      (8 * CPF)   // bwd region offset (halves)
#define LDS_H   (8 * CPF + 8 * CPB)   // 22656 halves = 45.3 KB
#define PADLEN  2307        // min(3K, L-1)
#define OFFSET  1539        // PADLEN - (K-1)
#define PBUF    (NB_ * GSM) // partial-g buffer stride (floats)

typedef _Float16 half8  __attribute__((ext_vector_type(8)));
typedef float    f32x4  __attribute__((ext_vector_type(4)));

#define MFMA16(a, b, c) __builtin_amdgcn_mfma_f32_16x16x32_f16((a), (b), (c), 0, 0, 0)

// ---------------------------------------------------------------------------
// Kernel 1: partial autocorrelation. grid (NB, 8, 4): j-range split 4-way.
// ---------------------------------------------------------------------------
__global__ __launch_bounds__(256) void bp_combine(
    const float* __restrict__ kern, float* __restrict__ gpart)
{
    __shared__ __align__(16) float ks[K_];
    const int o   = blockIdx.x;
    const int jc  = blockIdx.z;
    const int tid = threadIdx.x;
    for (int i = tid; i < K_; i += 256) ks[i] = kern[o * K_ + i];
    __syncthreads();

    const int m = blockIdx.y * 194 + tid;
    if (tid < 194 && m < GSM) {
        float acc = 0.f;
        int jlo = (m > K_ - 1) ? (m - (K_ - 1)) : 0;
        int jhi = (m < K_ - 1) ? m : (K_ - 1);
        if (jlo < jc * 193) jlo = jc * 193;
        if (jhi > jc * 193 + 192) jhi = jc * 193 + 192;
        for (int j = jlo; j <= jhi; ++j)
            acc = fmaf(ks[K_ - 1 - j], ks[m - j], acc);
        gpart[jc * PBUF + o * GSM + m] = acc;
    }
}

// ---------------------------------------------------------------------------
// Kernel 2: folded filter g' packed for mfma_f32_16x16x32_f16 A-fragments.
// g'[tap<768] = g[tap]; g'[768] = g[768]/2; g'[>768] = 0. Scaled x1024.
// Fragment f = (step*2 + tau)*64 + l: elem e = g'[o = 16*tau + (l&15),
//                                               32*step + 8*(l>>4) + e]
// ---------------------------------------------------------------------------
__global__ __launch_bounds__(256) void bp_pack(
    const float* __restrict__ gpart, _Float16* __restrict__ gbuf)
{
    const int t = blockIdx.x * 256 + threadIdx.x;
    if (t >= NSTP3 * 2 * 64) return;
    const int l    = t & 63;
    const int tau  = (t >> 6) & 1;
    const int step = t >> 7;
    const int g4   = l >> 4;
    const int o    = 16 * tau + (l & 15);
    half8 f;
    #pragma unroll
    for (int e = 0; e < 8; ++e) {
        const int tap = 32 * step + 8 * g4 + e;
        float v = 0.f;
        if (o < NB_ && tap <= 768) {
            const int idx = o * GSM + tap;
            const float gg = gpart[idx] + gpart[PBUF + idx] +
                             gpart[2 * PBUF + idx] + gpart[3 * PBUF + idx];
            v = gg * (tap == 768 ? 512.0f : 1024.0f);
        }
        f[e] = (_Float16)v;
    }
    *((half8*)gbuf + t) = f;
}

// ---------------------------------------------------------------------------
// Kernel 3 (folded, 16x16x32): z[t] = sum_k g'[k]*(xp[t'+k]+xp[t'+1536-k]),
// 25 K-steps of 32 taps. Per wave: 8 x 16-t subtiles, 2 o-tiles (bands 0-15,
// 16-19). Folded B-operand = R[(p+q)&7] + Rb[(p-q)&7] (fwd Toeplitz + bwd
// Hankel rings, 2+2 refills/step), shared by both o-tiles -> 16 MFMA/step.
// g' A-fragments from global (L2-resident), 2-step prefetch ring.
// ---------------------------------------------------------------------------
__global__ __launch_bounds__(256, 2) void bp_mfma(
    const float* __restrict__ x, const _Float16* __restrict__ gbuf,
    float* __restrict__ out)
{
    __shared__ __align__(16) _Float16 lds[LDS_H];

    const int blk  = blockIdx.x;
    const int tile = blk & 15;              // L/TB = 16
    const int b    = blk >> 4;
    const int tid  = threadIdx.x;
    const int l    = tid & 63;
    const int w    = tid >> 6;

    const int T0 = tile * TB;
    const int P0 = T0 + OFFSET;
    const float* __restrict__ xrow = x + b * L_;

    // ---- two-phase staging: global loads first, then LDS parity-copy writes
    // fwd: xf[i] = xp[P0 + i], i in [0, NWF)
    // bwd: xr[j] = xp[P0 + 2160 - j], j in [0, NWB)
    float fv[6], bv[6];
    #pragma unroll
    for (int r = 0; r < 6; ++r) {
        const int i = tid + 256 * r;
        if (i < NWF) {
            const int p = P0 + i;
            fv[r] = (p < PADLEN) ? -xrow[PADLEN - p]
                  : (p < PADLEN + L_) ? xrow[p - PADLEN]
                  : -xrow[(L_ - 2) + (PADLEN + L_) - p];
        }
        if (i < NWB) {
            const int p2 = P0 + 2160 - i;
            bv[r] = (p2 < PADLEN) ? -xrow[PADLEN - p2]
                  : (p2 < PADLEN + L_) ? xrow[p2 - PADLEN]
                  : -xrow[(L_ - 2) + (PADLEN + L_) - p2];
        }
    }
    #pragma unroll
    for (int r = 0; r < 6; ++r) {
        const int i = tid + 256 * r;
        if (i < NWF) {
            const _Float16 h = (_Float16)fv[r];
            #pragma unroll
            for (int cc = 0; cc < 8; ++cc)
                if (i - cc >= 0) lds[cc * CPF + (i - cc)] = h;
        }
        if (i < NWB) {
            const _Float16 h = (_Float16)bv[r];
            #pragma unroll
            for (int cc = 0; cc < 8; ++cc)
                if (i - cc >= 0) lds[XB + cc * CPB + (i - cc)] = h;
        }
    }
    __syncthreads();          // the only barrier

    const int g4 = l >> 4;                  // k-group 0..3
    const int t4 = l & 15;                  // t within subtile / A row
    const int cf = l & 7;                   // fwd parity copy (pos mod 8)
    const int cb = (16 - t4) & 7;           // bwd parity copy (jb mod 8)

    f32x4 acc0[8], acc1[8];
    #pragma unroll
    for (int q = 0; q < 8; ++q) {
        acc0[q] = (f32x4){0.f, 0.f, 0.f, 0.f};
        acc1[q] = (f32x4){0.f, 0.f, 0.f, 0.f};
    }

    // fwd slot a: per-lane pos = base_f + 16a, base_f = 128w + t4 + 8*g4
    // bwd slot b: per-lane pos = base_b + 16b, base_b = 624 - 128w - t4 + 8*g4
    const int base_f = 128 * w + t4 + 8 * g4;
    const int base_b = 624 - 128 * w - t4 + 8 * g4;
    const char* lbf0 = (const char*)lds + 2 * (cf * CPF + (base_f - cf));
    const char* lbb0 = (const char*)lds + 2 * (XB + cb * CPB + (base_b - cb));

    half8 R[8], Rb[8];
    #pragma unroll
    for (int a = 0; a < 8; ++a)
        R[a] = *(const half8*)(lbf0 + 32 * a);
    Rb[0] = *(const half8*)(lbb0);
    #pragma unroll
    for (int j = 1; j < 8; ++j)
        Rb[j] = *(const half8*)(lbb0 - 32 * (8 - j));

    // g A-fragment ring: ga[S&1][tau]; prefetch distance 2 steps.
    const half8* __restrict__ gp = (const half8*)gbuf + l;
    half8 ga[2][2];
    ga[0][0] = gp[0];   ga[0][1] = gp[64];
    ga[1][0] = gp[128]; ga[1][1] = gp[192];

    for (int n = 0; n < 6; ++n) {           // 6 x 4 steps = 24
        const char* lbf = lbf0 + 256 * n;   // 64 * 4n
        const char* lbb = lbb0 + 256 * n;
        const half8* gpn = gp + 128 * 4 * n;
        #pragma unroll
        for (int k4 = 0; k4 < 4; ++k4) {    // S = 4n + k4; all indices static
            const int p = 2 * k4;
            const int sel = k4 & 1;
            __builtin_amdgcn_s_setprio(1);
            #pragma unroll
            for (int q = 0; q < 8; ++q) {
                const half8 Bq = R[(p + q) & 7] + Rb[(p + 8 - q) & 7];
                acc0[q] = MFMA16(ga[sel][0], Bq, acc0[q]);
                acc1[q] = MFMA16(ga[sel][1], Bq, acc1[q]);
            }
            __builtin_amdgcn_s_setprio(0);
            // refills: fwd a = 2S+8, 2S+9 -> bytes 64S+256, +288
            R[p & 7]        = *(const half8*)(lbf + 64 * k4 + 256);
            R[(p + 1) & 7]  = *(const half8*)(lbf + 64 * k4 + 288);
            // bwd b = 2S+1, 2S+2 -> bytes 64S+32, +64
            Rb[(p + 1) & 7] = *(const half8*)(lbb + 64 * k4 + 32);
            Rb[(p + 2) & 7] = *(const half8*)(lbb + 64 * k4 + 64);
            // g prefetch step S+2 (padded with zeros to NSTP3: blind-safe)
            ga[sel][0] = gpn[(k4 + 2) * 128];
            ga[sel][1] = gpn[(k4 + 2) * 128 + 64];
        }
    }

    // tail: S = 24, p = 48&7 = 0; rings hold a=48..55, b=41..48; ga[24&1=0]
    __builtin_amdgcn_s_setprio(1);
    #pragma unroll
    for (int q = 0; q < 8; ++q) {
        const half8 Bq = R[q & 7] + Rb[(8 - q) & 7];
        acc0[q] = MFMA16(ga[0][0], Bq, acc0[q]);
        acc1[q] = MFMA16(ga[0][1], Bq, acc1[q]);
    }
    __builtin_amdgcn_s_setprio(0);

    // D layout (m89, 16x16): col = l&15, row = (l>>4)*4 + r
    const float sc = 1.0f / 1024.0f;
    #pragma unroll
    for (int q = 0; q < 8; ++q) {
        const int tb = T0 + 128 * w + 16 * q + t4;
        #pragma unroll
        for (int r = 0; r < 4; ++r) {
            const int o0 = 4 * g4 + r;          // bands 0..15
            __builtin_nontemporal_store(acc0[q][r] * sc,
                                        &out[((b * NB_ + o0) << 13) + tb]);
        }
        if (g4 == 0) {
            #pragma unroll
            for (int r = 0; r < 4; ++r) {
                const int o1 = 16 + r;          // bands 16..19
                __builtin_nontemporal_store(acc1[q][r] * sc,
                                            &out[((b * NB_ + o1) << 13) + tb]);
            }
        }
    }
}

extern "C" void kernel_launch(void* const* d_in, const int* in_sizes, int n_in,
                              void* d_out, int out_size, void* d_ws, size_t ws_size,
                              hipStream_t stream)
{
    const float* x    = (const float*)d_in[0];   // (B,1,L) f32
    const float* kern = (const float*)d_in[1];   // (NB,K) f32
    float*       out  = (float*)d_out;           // (B,1,NB,L) f32

    float*    gpart = (float*)d_ws;                           // 496640 B
    _Float16* gbuf  = (_Float16*)((char*)d_ws + 496640);      // 28*2*64*16 = 57344 B

    bp_combine<<<dim3(NB_, 8, 4), 256, 0, stream>>>(kern, gpart);
    bp_pack<<<14, 256, 0, stream>>>(gpart, gbuf);
    bp_mfma<<<B_ * (L_ / TB), 256, 0, stream>>>(x, gbuf, out);
}